// Round 10
// baseline (124.458 us; speedup 1.0000x reference)
//
#include <hip/hip_runtime.h>

// ---------- types / helpers ----------
typedef _Float16 f16x8 __attribute__((ext_vector_type(8)));
typedef float f32x4 __attribute__((ext_vector_type(4)));
typedef const __attribute__((address_space(1))) void* as1_cvp;
typedef __attribute__((address_space(3))) void* as3_vp;

__device__ __forceinline__ float tanh_fast(float x){
  // tanh(x) = 1 - 2/(1+exp2(2*log2e*x)); exact at saturation
  float e = __builtin_amdgcn_exp2f(x * 2.88539008177793f);
  return 1.f - 2.f * __builtin_amdgcn_rcpf(1.f + e);
}
__device__ __forceinline__ unsigned short f2h(float f){
  return __builtin_bit_cast(unsigned short, (_Float16)f);
}
__device__ __forceinline__ float h2f(unsigned short u){
  return (float)__builtin_bit_cast(_Float16, u);
}
__device__ __forceinline__ f32x4 mfma16(f16x8 a, f16x8 b, f32x4 c){
  return __builtin_amdgcn_mfma_f32_16x16x32_f16(a, b, c, 0, 0, 0);
}

// A-fragment from an LDS [32][128] f16 tile.
__device__ __forceinline__ f16x8 ldsA(const unsigned short* buf, int rb, int s, int lane){
  return *(const f16x8*)(buf + (rb*16 + (lane&15))*128 + s*32 + ((lane>>4)<<3));
}

// ---------- PREP: weight transposes + k1 hidden + xT transpose ----------
// wt2 tiled+swizzled: element (col,k), col=i*128+colL, chalf=colL>>6, c64=colL&63:
//   dst = (i*2+chalf)*8192 + c64*128 + (k ^ ((col&15)<<3))
// -> k2's 16KB tile (i,chalf) is contiguous; ds_read_b128 conflict-free.
__global__ __launch_bounds__(256) void prep_kernel(
    const float* __restrict__ obs, const float* __restrict__ hw1,
    const float* __restrict__ hb1, const float* __restrict__ hw2,
    const float* __restrict__ vw1, const float* __restrict__ vw2,
    const float* __restrict__ aw1, const float* __restrict__ aw2,
    unsigned short* __restrict__ wt2, unsigned short* __restrict__ vw1t,
    unsigned short* __restrict__ vw2t, unsigned short* __restrict__ aw1t,
    unsigned short* __restrict__ aw2t, unsigned short* __restrict__ h16,
    float* __restrict__ xT){
  int b = blockIdx.x, t = threadIdx.x;
  if (b < 1616){
    __shared__ float tile[32][33];
    const float* in; unsigned short* out; int R, C, bx, by; bool swz;
    if (b < 1536)      { in=hw2; out=wt2;  R=128; C=12288; bx=b%384;      by=b/384; swz=true; }
    else if (b < 1552) { int q=b-1536; in=vw1; out=vw1t; R=128; C=128; bx=q&3; by=q>>2; swz=false; }
    else if (b < 1568) { int q=b-1552; in=vw2; out=vw2t; R=128; C=128; bx=q&3; by=q>>2; swz=false; }
    else if (b < 1600) { int q=b-1568; in=aw1; out=aw1t; R=256; C=128; bx=q&3; by=q>>2; swz=false; }
    else               { int q=b-1600; in=aw2; out=aw2t; R=128; C=128; bx=q&3; by=q>>2; swz=false; }
    int c0=bx*32, r0=by*32, tx=t&31, ty=t>>5;
    #pragma unroll
    for (int j=ty; j<32; j+=8) tile[j][tx] = in[(size_t)(r0+j)*C + c0 + tx];
    __syncthreads();
    if (swz){
      #pragma unroll
      for (int j=ty; j<32; j+=8){
        int col = c0+j, k = r0+tx;
        int i = col>>7, colL = col&127;
        int chalf = colL>>6, c64 = colL&63;
        out[(size_t)(i*2 + chalf)*8192 + c64*128 + (k ^ ((col&15)<<3))] = f2h(tile[tx][j]);
      }
    } else {
      #pragma unroll
      for (int j=ty; j<32; j+=8) out[(size_t)(c0+j)*R + r0 + tx] = f2h(tile[tx][j]);
    }
  } else {
    __shared__ float w_s[96*128];
    __shared__ float x_s[32*97];   // pad 97: conflict-free transpose read
    __shared__ float b_s[128];
    int n0 = (b-1616)*32;
    for (int idx=t; idx<96*128; idx+=256) w_s[idx] = hw1[idx];
    if (t < 128) b_s[t] = hb1[t];
    for (int idx=t; idx<32*96; idx+=256){
      int r = idx/96, i = idx - r*96;
      int n = n0 + r; int bb = n>>3, l = n&7;
      x_s[r*97+i] = (i<64) ? obs[bb*360 + i] : obs[bb*360 + 104 + (l<<5) + (i-64)];
    }
    __syncthreads();
    // xT[i][n] transpose-out (coalesced over n)
    for (int e=t; e<96*32; e+=256){
      int i = e>>5, r = e&31;
      xT[(size_t)i*8192 + n0 + r] = x_s[r*97 + i];
    }
    for (int e=t; e<32*128; e+=256){
      int r = e>>7, o = e&127;
      float acc = b_s[o];
      const float* xr = &x_s[r*97];
      #pragma unroll 4
      for (int i=0;i<96;++i) acc = fmaf(xr[i], w_s[i*128+o], acc);
      h16[(size_t)(n0+r)*128 + o] = f2h(tanh_fast(acc));
    }
  }
}

// ---------- K2: LDS-staged hypernet GEMM + tanh + x-contraction ----------
// grid 1024: bid = rt*16 + chalf*8 + iseg. Block: 256 thr (4 waves x 32 rows =
// 128 rows), 64 cols (chalf), 12 i's (iseg). LDS 32KB -> 4 blocks/CU, 16 waves.
// wt2 L2 traffic 201MB. x from xT (direct f32x4). 8-way atomicAdd into accg.
__device__ __forceinline__ void stage_tile(const unsigned short* gsrc,
                                           unsigned short* lbuf, int t){
  const unsigned short* g = gsrc + t*8;
  unsigned short* l = lbuf + t*8;
  #pragma unroll
  for (int p=0;p<4;++p)
    __builtin_amdgcn_global_load_lds((as1_cvp)(g + p*2048), (as3_vp)(l + p*2048), 16, 0, 0);
}

__global__ __launch_bounds__(256, 4) void k2_hyper(
    const float* __restrict__ xT, const unsigned short* __restrict__ h16,
    const unsigned short* __restrict__ wt2, const float* __restrict__ hb2,
    float* __restrict__ accg){
  __shared__ unsigned short bts[2][8192];   // 2 x 16KB swizzled tiles
  int t = threadIdx.x, lane = t & 63, rg = t >> 6;
  int bid = blockIdx.x;
  int rt = bid >> 4, chalf = (bid >> 3) & 1, iseg = bid & 7;
  int R0 = rt*128, C0 = chalf*64, ibase = iseg*12;
  int cl   = lane & 15;
  int kof  = (lane>>4) << 3;
  int rloc = (lane>>4) << 2;
  int sx   = cl << 3;                        // read-side XOR = (c64&15)<<3 = cl<<3

  // A fragments: this wave's 32 rows, i-invariant
  f16x8 af[2][4];
  #pragma unroll
  for (int rb=0; rb<2; ++rb)
    #pragma unroll
    for (int s=0; s<4; ++s)
      af[rb][s] = *(const f16x8*)(h16 + (size_t)(R0 + rg*32 + rb*16 + cl)*128 + s*32 + kof);

  stage_tile(wt2 + (size_t)(ibase*2 + chalf)*8192, bts[0], t);
  __syncthreads();

  float facc[2][4][4];
  #pragma unroll
  for (int rb=0;rb<2;++rb)
    #pragma unroll
    for (int ch=0;ch<4;++ch)
      #pragma unroll
      for (int reg=0;reg<4;++reg) facc[rb][ch][reg] = 0.f;

  for (int it=0; it<12; ++it){
    const unsigned short* lb = bts[it&1];
    if (it < 11) stage_tile(wt2 + (size_t)((ibase+it+1)*2 + chalf)*8192, bts[(it+1)&1], t);
    f32x4 xa = *(const f32x4*)(xT + (size_t)(ibase+it)*8192 + R0 + rg*32 + rloc);
    f32x4 xb = *(const f32x4*)(xT + (size_t)(ibase+it)*8192 + R0 + rg*32 + 16 + rloc);
    const float* bias_p = hb2 + (ibase+it)*128 + C0;
    #pragma unroll
    for (int ch=0; ch<4; ++ch){
      int c64 = ch*16 + cl;
      const unsigned short* bp = lb + c64*128;
      f16x8 b0 = *(const f16x8*)(bp + ((  0+kof)^sx));
      f16x8 b1 = *(const f16x8*)(bp + (( 32+kof)^sx));
      f16x8 b2 = *(const f16x8*)(bp + (( 64+kof)^sx));
      f16x8 b3 = *(const f16x8*)(bp + (( 96+kof)^sx));
      float bi = bias_p[c64];
      f32x4 a0 = {bi,bi,bi,bi}, a1 = {bi,bi,bi,bi};
      a0 = mfma16(af[0][0], b0, a0); a1 = mfma16(af[1][0], b0, a1);
      a0 = mfma16(af[0][1], b1, a0); a1 = mfma16(af[1][1], b1, a1);
      a0 = mfma16(af[0][2], b2, a0); a1 = mfma16(af[1][2], b2, a1);
      a0 = mfma16(af[0][3], b3, a0); a1 = mfma16(af[1][3], b3, a1);
      #pragma unroll
      for (int reg=0;reg<4;++reg){
        facc[0][ch][reg] = fmaf(xa[reg], tanh_fast(a0[reg]), facc[0][ch][reg]);
        facc[1][ch][reg] = fmaf(xb[reg], tanh_fast(a1[reg]), facc[1][ch][reg]);
      }
    }
    __syncthreads();
  }

  #pragma unroll
  for (int rb=0; rb<2; ++rb)
    #pragma unroll
    for (int ch=0; ch<4; ++ch)
      #pragma unroll
      for (int reg=0; reg<4; ++reg)
        atomicAdd(&accg[(size_t)(R0 + rg*32 + rb*16 + rloc + reg)*128 + C0 + ch*16 + cl],
                  facc[rb][ch][reg]);
}

// ---------- K3: per-batch landmark mean of tanh(accg) -> mean16 ----------
__global__ __launch_bounds__(256) void k3_mean(const float* __restrict__ accg,
    unsigned short* __restrict__ mean16){
  int t = threadIdx.x, B0 = blockIdx.x*4;
  for (int task=t; task<512; task+=256){
    int bl = task>>7, o = task&127;
    float m = 0.f;
    #pragma unroll
    for (int l=0;l<8;++l)
      m += tanh_fast(accg[(size_t)((B0 + bl)*8 + l)*128 + o]);
    mean16[(size_t)(B0 + bl)*128 + o] = f2h(m * 0.125f);
  }
}

// ---------- K4: emb from accg + fused MLP chain + softmax + final ----------
template<int KS>
__device__ __forceinline__ void stage(const unsigned short* inA, const unsigned short* inB,
    const unsigned short* wt, const float* bias, unsigned short* outb, int w, int lane){
  #pragma unroll
  for (int obl=0; obl<2; ++obl){
    int col = ((w*2+obl)<<4) + (lane&15);
    f32x4 a0 = {0.f,0.f,0.f,0.f}, a1v = {0.f,0.f,0.f,0.f};
    #pragma unroll
    for (int s=0;s<KS;++s){
      f16x8 bfr = *(const f16x8*)(wt + (size_t)col*(KS*32) + s*32 + ((lane>>4)<<3));
      f16x8 aa0, aa1;
      if (KS==8 && s>=4){ aa0 = ldsA(inB,0,s-4,lane); aa1 = ldsA(inB,1,s-4,lane); }
      else              { aa0 = ldsA(inA,0,s,lane);   aa1 = ldsA(inA,1,s,lane);   }
      a0  = mfma16(aa0, bfr, a0);
      a1v = mfma16(aa1, bfr, a1v);
    }
    float bb = bias[col];
    #pragma unroll
    for (int reg=0;reg<4;++reg){
      int r0 = ((lane>>4)<<2) + reg;
      outb[r0*128 + col]      = f2h(tanh_fast(a0[reg] + bb));
      outb[(16+r0)*128 + col] = f2h(tanh_fast(a1v[reg] + bb));
    }
  }
}

__global__ __launch_bounds__(256) void k4_mlp(
    const float* __restrict__ accg, const unsigned short* __restrict__ mean16,
    const unsigned short* __restrict__ vw1t, const unsigned short* __restrict__ vw2t,
    const unsigned short* __restrict__ aw1t, const unsigned short* __restrict__ aw2t,
    const float* __restrict__ vb1, const float* __restrict__ vb2,
    const float* __restrict__ ab1, const float* __restrict__ ab2,
    const float* __restrict__ aw3, const float* __restrict__ ab3,
    float* __restrict__ outp){
  __shared__ unsigned short bufE[32*128];
  __shared__ unsigned short bufM[32*128];
  __shared__ unsigned short bufA[32*128];
  __shared__ float fin[4*128];
  __shared__ float lp[32*8];
  __shared__ float att_s[32];
  int t = threadIdx.x, lane = t&63, w = t>>6;
  int R0 = blockIdx.x*32;

  // emb = tanh(accg) for our 32 rows
  for (int idx=t; idx<4096; idx+=256)
    bufE[idx] = f2h(tanh_fast(accg[(size_t)R0*128 + idx]));
  // mean_rep faithful ordering: row n pairs with mean[(n % 1024)]
  for (int idx=t; idx<512; idx+=256){
    int r = idx>>4, c8 = (idx&15)<<3;
    int n = R0 + r;
    *(uint4*)(bufM + r*128 + c8) = *(const uint4*)(mean16 + (size_t)(n & 1023)*128 + c8);
  }
  for (int idx=t; idx<512; idx+=256) fin[idx] = 0.f;
  __syncthreads();

  stage<8>(bufE, bufM, aw1t, ab1, bufA, w, lane);
  __syncthreads();
  stage<4>(bufA, nullptr, aw2t, ab2, bufM, w, lane);
  __syncthreads();
  {
    int r = t>>3, seg = t&7;
    float p = 0.f;
    const unsigned short* row = bufM + r*128 + seg*16;
    const float* w3 = aw3 + seg*16;
    #pragma unroll
    for (int k=0;k<16;++k) p += h2f(row[k]) * w3[k];
    lp[r*8+seg] = p;
  }
  __syncthreads();
  if (t < 4){
    float lg[8]; float mx = -1e30f;
    for (int l=0;l<8;++l){
      float s = ab3[0];
      #pragma unroll
      for (int sg=0;sg<8;++sg) s += lp[(t*8+l)*8+sg];
      lg[l] = s; mx = fmaxf(mx, s);
    }
    float sum = 0.f;
    for (int l=0;l<8;++l){ lg[l] = __builtin_amdgcn_exp2f((lg[l]-mx)*1.44269504089f); sum += lg[l]; }
    float inv = __builtin_amdgcn_rcpf(sum);
    for (int l=0;l<8;++l) att_s[t*8+l] = lg[l]*inv;
  }
  __syncthreads();
  stage<4>(bufE, nullptr, vw1t, vb1, bufA, w, lane);
  __syncthreads();
  {
    #pragma unroll
    for (int obl=0; obl<2; ++obl){
      int col = ((w*2+obl)<<4) + (lane&15);
      f32x4 a0 = {0.f,0.f,0.f,0.f}, a1v = {0.f,0.f,0.f,0.f};
      #pragma unroll
      for (int s=0;s<4;++s){
        f16x8 bfr = *(const f16x8*)(vw2t + (size_t)col*128 + s*32 + ((lane>>4)<<3));
        a0  = mfma16(ldsA(bufA,0,s,lane), bfr, a0);
        a1v = mfma16(ldsA(bufA,1,s,lane), bfr, a1v);
      }
      float bb = vb2[col];
      #pragma unroll
      for (int reg=0;reg<4;++reg){
        int r0 = ((lane>>4)<<2) + reg;
        float v0 = tanh_fast(a0[reg]+bb);
        float v1 = tanh_fast(a1v[reg]+bb);
        atomicAdd(&fin[((r0)>>3)*128 + col],    att_s[r0]    * v0);
        atomicAdd(&fin[((16+r0)>>3)*128 + col], att_s[16+r0] * v1);
      }
    }
  }
  __syncthreads();
  for (int idx=t; idx<512; idx+=256){
    int b_loc = idx>>7, o = idx&127;
    outp[(size_t)(R0/8 + b_loc)*128 + o] = fin[idx];
  }
}

// ---------- launch ----------
extern "C" void kernel_launch(void* const* d_in, const int* in_sizes, int n_in,
                              void* d_out, int out_size, void* d_ws, size_t ws_size,
                              hipStream_t stream){
  const float* obs = (const float*)d_in[0];
  const float* hw1 = (const float*)d_in[3];
  const float* hb1 = (const float*)d_in[4];
  const float* hw2 = (const float*)d_in[5];
  const float* hb2 = (const float*)d_in[6];
  const float* vw1 = (const float*)d_in[7];
  const float* vb1 = (const float*)d_in[8];
  const float* vw2 = (const float*)d_in[9];
  const float* vb2 = (const float*)d_in[10];
  const float* aw1 = (const float*)d_in[11];
  const float* ab1 = (const float*)d_in[12];
  const float* aw2 = (const float*)d_in[13];
  const float* ab2 = (const float*)d_in[14];
  const float* aw3 = (const float*)d_in[15];
  const float* ab3 = (const float*)d_in[16];

  char* ws = (char*)d_ws;
  unsigned short* wt2    = (unsigned short*)(ws);             // 3,145,728 B
  unsigned short* mean16 = (unsigned short*)(ws);             //   262,144 B (alias; wt2 dead after k2)
  unsigned short* h16    = (unsigned short*)(ws + 3145728);   // 2,097,152 B
  float*          accg   = (float*)        (ws + 5242880);    // 4,194,304 B
  float*          xT     = (float*)        (ws + 9437184);    // 3,145,728 B (96 x 8192 f32)
  unsigned short* vw1t   = (unsigned short*)(ws + 12582912);  //    32,768 B
  unsigned short* vw2t   = (unsigned short*)(ws + 12615680);  //    32,768 B
  unsigned short* aw1t   = (unsigned short*)(ws + 12648448);  //    65,536 B
  unsigned short* aw2t   = (unsigned short*)(ws + 12713984);  //    32,768 B  (end 12,746,752)
  float* outp = (float*)d_out;

  hipMemsetAsync(accg, 0, 8192*128*sizeof(float), stream);
  prep_kernel<<<1872, 256, 0, stream>>>(obs, hw1, hb1, hw2, vw1, vw2, aw1, aw2,
                                        wt2, vw1t, vw2t, aw1t, aw2t, h16, xT);
  k2_hyper<<<1024, 256, 0, stream>>>(xT, h16, wt2, hb2, accg);
  k3_mean<<<256, 256, 0, stream>>>(accg, mean16);
  k4_mlp<<<256, 256, 0, stream>>>(accg, mean16, vw1t, vw2t, aw1t, aw2t,
                                  vb1, vb2, ab1, ab2, aw3, ab3, outp);
}

// Round 11
// 118.619 us; speedup vs baseline: 1.0492x; 1.0492x over previous
//
#include <hip/hip_runtime.h>

// ---------- types / helpers ----------
typedef _Float16 f16x8 __attribute__((ext_vector_type(8)));
typedef float f32x4 __attribute__((ext_vector_type(4)));
typedef const __attribute__((address_space(1))) void* as1_cvp;
typedef __attribute__((address_space(3))) void* as3_vp;

#define LOG2E2 2.88539008177793f   // 2*log2(e)

__device__ __forceinline__ float tanh_fast(float x){
  float e = __builtin_amdgcn_exp2f(x * LOG2E2);
  return 1.f - 2.f * __builtin_amdgcn_rcpf(1.f + e);
}
__device__ __forceinline__ unsigned short f2h(float f){
  return __builtin_bit_cast(unsigned short, (_Float16)f);
}
__device__ __forceinline__ float h2f(unsigned short u){
  return (float)__builtin_bit_cast(_Float16, u);
}
__device__ __forceinline__ f32x4 mfma16(f16x8 a, f16x8 b, f32x4 c){
  return __builtin_amdgcn_mfma_f32_16x16x32_f16(a, b, c, 0, 0, 0);
}
__device__ __forceinline__ f16x8 ldsA(const unsigned short* buf, int rb, int s, int lane){
  return *(const f16x8*)(buf + (rb*16 + (lane&15))*128 + s*32 + ((lane>>4)<<3));
}

// ---------- PREP ----------
// hw2 -> wt2 tiles: tile(i,chalf) is 16KB contiguous, layout [kg(16)][c64(64)][k&7(8)]
// (k-granule-major: k2 B-reads are LINEAR 16B/lane; prep writes fully coalesced).
// blocks: [0,768) hw2 (i=b>>3, chalf=(b&7)>>2, kq=b&3); [768,784) vw1; [784,800) vw2;
// [800,832) aw1; [832,848) aw2; [848,1104) k1 (32 rows each) + xT transpose.
__global__ __launch_bounds__(256) void prep_kernel(
    const float* __restrict__ obs, const float* __restrict__ hw1,
    const float* __restrict__ hb1, const float* __restrict__ hw2,
    const float* __restrict__ vw1, const float* __restrict__ vw2,
    const float* __restrict__ aw1, const float* __restrict__ aw2,
    unsigned short* __restrict__ wt2, unsigned short* __restrict__ vw1t,
    unsigned short* __restrict__ vw2t, unsigned short* __restrict__ aw1t,
    unsigned short* __restrict__ aw2t, unsigned short* __restrict__ h16,
    float* __restrict__ xT){
  int b = blockIdx.x, t = threadIdx.x;
  if (b < 768){
    __shared__ float xp[64][33];          // [col-offset][k-offset]
    int i = b >> 3, chalf = (b&7) >> 2, kq = b & 3;
    int c0 = i*128 + chalf*64, r0 = kq*32;
    int tx = t & 63, j0 = t >> 6;
    #pragma unroll
    for (int j = j0; j < 32; j += 4)
      xp[tx][j] = hw2[(size_t)(r0+j)*12288 + c0 + tx];
    __syncthreads();
    // thread: c64 = t&63, kg_local = t>>6; one coalesced uint4 store
    int c = t & 63, kgl = t >> 6;
    unsigned short us[8];
    #pragma unroll
    for (int q=0;q<8;++q) us[q] = f2h(xp[c][kgl*8 + q]);
    size_t dst = (size_t)(i*2 + chalf)*8192 + (size_t)(kq*4 + kgl)*512 + c*8;
    *(uint4*)(wt2 + dst) = *(uint4*)us;
  } else if (b < 848){
    __shared__ float tile[32][33];
    const float* in; unsigned short* out; int R, bx, by;
    if (b < 784)      { int q=b-768; in=vw1; out=vw1t; R=128; bx=q&3; by=q>>2; }
    else if (b < 800) { int q=b-784; in=vw2; out=vw2t; R=128; bx=q&3; by=q>>2; }
    else if (b < 832) { int q=b-800; in=aw1; out=aw1t; R=256; bx=q&3; by=q>>2; }
    else              { int q=b-832; in=aw2; out=aw2t; R=128; bx=q&3; by=q>>2; }
    int c0=bx*32, r0=by*32, tx=t&31, ty=t>>5;
    #pragma unroll
    for (int j=ty; j<32; j+=8) tile[j][tx] = in[(size_t)(r0+j)*128 + c0 + tx];
    __syncthreads();
    #pragma unroll
    for (int j=ty; j<32; j+=8) out[(size_t)(c0+j)*R + r0 + tx] = f2h(tile[tx][j]);
  } else {
    __shared__ float w_s[96*128];
    __shared__ float x_s[32*97];
    __shared__ float b_s[128];
    int n0 = (b-848)*32;
    for (int idx=t; idx<96*128; idx+=256) w_s[idx] = hw1[idx];
    if (t < 128) b_s[t] = hb1[t];
    for (int idx=t; idx<32*96; idx+=256){
      int r = idx/96, i = idx - r*96;
      int n = n0 + r; int bb = n>>3, l = n&7;
      x_s[r*97+i] = (i<64) ? obs[bb*360 + i] : obs[bb*360 + 104 + (l<<5) + (i-64)];
    }
    __syncthreads();
    for (int e=t; e<96*32; e+=256){
      int i = e>>5, r = e&31;
      xT[(size_t)i*8192 + n0 + r] = x_s[r*97 + i];
    }
    for (int e=t; e<32*128; e+=256){
      int r = e>>7, o = e&127;
      float acc = b_s[o];
      const float* xr = &x_s[r*97];
      #pragma unroll 4
      for (int i=0;i<96;++i) acc = fmaf(xr[i], w_s[i*128+o], acc);
      h16[(size_t)(n0+r)*128 + o] = f2h(tanh_fast(acc));
    }
  }
}

// ---------- K2: counted-vmcnt pipelined hypernet GEMM + tanh + x-contraction ----
// grid 1024: bid = rt*16 + chalf*8 + iseg (iseg = bid%8 -> one iseg per XCD).
// Block 256 thr: 128 rows x 64 cols x 12 i. LDS: 2x16KB tiles + x 6KB + bias 3KB.
// Inner loop has ZERO VMEM (x/bias in LDS) -> manual s_waitcnt vmcnt(0) + raw
// s_barrier gives true 1-iteration prefetch depth. waves_per_eu(3,4): VGPR>=128.
__device__ __forceinline__ void stage_tile(const unsigned short* gsrc,
                                           unsigned short* lbuf, int t){
  const unsigned short* g = gsrc + t*8;
  unsigned short* l = lbuf + t*8;
  #pragma unroll
  for (int p=0;p<4;++p)
    __builtin_amdgcn_global_load_lds((as1_cvp)(g + p*2048), (as3_vp)(l + p*2048), 16, 0, 0);
}

__global__ __launch_bounds__(256) __attribute__((amdgpu_waves_per_eu(3,4)))
void k2_hyper(const float* __restrict__ xT, const unsigned short* __restrict__ h16,
              const unsigned short* __restrict__ wt2, const float* __restrict__ hb2,
              float* __restrict__ accg){
  __shared__ unsigned short bts[2][8192];   // 2 x 16KB tiles [kg][c64][k&7]
  __shared__ float x_s[12*128];
  __shared__ float bias_s[12*64];
  int t = threadIdx.x, lane = t & 63, rg = t >> 6;
  int bid = blockIdx.x;
  int rt = bid >> 4, chalf = (bid >> 3) & 1, iseg = bid & 7;
  int R0 = rt*128, C0 = chalf*64, ibase = iseg*12;
  int cl   = lane & 15;
  int g    = lane >> 4;
  int kof  = g << 3;
  int rloc = g << 2;

  // stage x slice (12x128) and bias slice (12x64) once
  for (int idx=t; idx<12*128; idx+=256){
    int il = idx>>7, r = idx&127;
    x_s[idx] = xT[(size_t)(ibase+il)*8192 + R0 + r];
  }
  for (int idx=t; idx<12*64; idx+=256){
    int il = idx>>6, c = idx&63;
    bias_s[idx] = hb2[(ibase+il)*128 + C0 + c];
  }

  // A fragments: this wave's 32 rows, i-invariant
  f16x8 af[2][4];
  #pragma unroll
  for (int rb=0; rb<2; ++rb)
    #pragma unroll
    for (int s=0; s<4; ++s)
      af[rb][s] = *(const f16x8*)(h16 + (size_t)(R0 + rg*32 + rb*16 + cl)*128 + s*32 + kof);

  stage_tile(wt2 + (size_t)(ibase*2 + chalf)*8192, bts[0], t);

  float facc[2][4][4];
  #pragma unroll
  for (int rb=0;rb<2;++rb)
    #pragma unroll
    for (int ch=0;ch<4;++ch)
      #pragma unroll
      for (int reg=0;reg<4;++reg) facc[rb][ch][reg] = 0.f;

  const f32x4 zero4 = {0.f,0.f,0.f,0.f};

  for (int it=0; it<12; ++it){
    // tile `it` loads were issued >=1 full iteration ago; x_s/bias_s covered at it==0
    asm volatile("s_waitcnt vmcnt(0)" ::: "memory");
    __builtin_amdgcn_s_barrier();
    __builtin_amdgcn_sched_barrier(0);
    const unsigned short* lb = bts[it&1];
    if (it < 11) stage_tile(wt2 + (size_t)((ibase+it+1)*2 + chalf)*8192, bts[(it+1)&1], t);

    f32x4 xa = *(const f32x4*)(x_s + it*128 + rg*32 + rloc);
    f32x4 xb = *(const f32x4*)(x_s + it*128 + rg*32 + 16 + rloc);
    #pragma unroll
    for (int ch=0; ch<4; ++ch){
      int c64 = ch*16 + cl;
      const unsigned short* bp = lb + c64*8 + g*512;   // [kg][c64][k&7]: linear 16B/lane
      f16x8 b0 = *(const f16x8*)(bp);
      f16x8 b1 = *(const f16x8*)(bp + 2048);
      f16x8 b2 = *(const f16x8*)(bp + 4096);
      f16x8 b3 = *(const f16x8*)(bp + 6144);
      float bi2 = bias_s[it*64 + c64] * LOG2E2;
      f32x4 a0 = zero4, a1 = zero4;
      a0 = mfma16(af[0][0], b0, a0); a1 = mfma16(af[1][0], b0, a1);
      a0 = mfma16(af[0][1], b1, a0); a1 = mfma16(af[1][1], b1, a1);
      a0 = mfma16(af[0][2], b2, a0); a1 = mfma16(af[1][2], b2, a1);
      a0 = mfma16(af[0][3], b3, a0); a1 = mfma16(af[1][3], b3, a1);
      #pragma unroll
      for (int reg=0;reg<4;++reg){
        float e0 = __builtin_amdgcn_exp2f(fmaf(a0[reg], LOG2E2, bi2));
        float e1 = __builtin_amdgcn_exp2f(fmaf(a1[reg], LOG2E2, bi2));
        float t0 = 1.f - 2.f*__builtin_amdgcn_rcpf(1.f + e0);
        float t1 = 1.f - 2.f*__builtin_amdgcn_rcpf(1.f + e1);
        facc[0][ch][reg] = fmaf(xa[reg], t0, facc[0][ch][reg]);
        facc[1][ch][reg] = fmaf(xb[reg], t1, facc[1][ch][reg]);
      }
    }
  }

  #pragma unroll
  for (int rb=0; rb<2; ++rb)
    #pragma unroll
    for (int ch=0; ch<4; ++ch)
      #pragma unroll
      for (int reg=0; reg<4; ++reg)
        atomicAdd(&accg[(size_t)(R0 + rg*32 + rb*16 + rloc + reg)*128 + C0 + ch*16 + cl],
                  facc[rb][ch][reg]);
}

// ---------- K3: per-batch landmark mean of tanh(accg) -> mean16 ----------
__global__ __launch_bounds__(256) void k3_mean(const float* __restrict__ accg,
    unsigned short* __restrict__ mean16){
  int t = threadIdx.x, B0 = blockIdx.x*4;
  for (int task=t; task<512; task+=256){
    int bl = task>>7, o = task&127;
    float m = 0.f;
    #pragma unroll
    for (int l=0;l<8;++l)
      m += tanh_fast(accg[(size_t)((B0 + bl)*8 + l)*128 + o]);
    mean16[(size_t)(B0 + bl)*128 + o] = f2h(m * 0.125f);
  }
}

// ---------- K4: emb from accg + fused MLP chain + softmax + final ----------
template<int KS>
__device__ __forceinline__ void stage(const unsigned short* inA, const unsigned short* inB,
    const unsigned short* wt, const float* bias, unsigned short* outb, int w, int lane){
  #pragma unroll
  for (int obl=0; obl<2; ++obl){
    int col = ((w*2+obl)<<4) + (lane&15);
    f32x4 a0 = {0.f,0.f,0.f,0.f}, a1v = {0.f,0.f,0.f,0.f};
    #pragma unroll
    for (int s=0;s<KS;++s){
      f16x8 bfr = *(const f16x8*)(wt + (size_t)col*(KS*32) + s*32 + ((lane>>4)<<3));
      f16x8 aa0, aa1;
      if (KS==8 && s>=4){ aa0 = ldsA(inB,0,s-4,lane); aa1 = ldsA(inB,1,s-4,lane); }
      else              { aa0 = ldsA(inA,0,s,lane);   aa1 = ldsA(inA,1,s,lane);   }
      a0  = mfma16(aa0, bfr, a0);
      a1v = mfma16(aa1, bfr, a1v);
    }
    float bb = bias[col];
    #pragma unroll
    for (int reg=0;reg<4;++reg){
      int r0 = ((lane>>4)<<2) + reg;
      outb[r0*128 + col]      = f2h(tanh_fast(a0[reg] + bb));
      outb[(16+r0)*128 + col] = f2h(tanh_fast(a1v[reg] + bb));
    }
  }
}

__global__ __launch_bounds__(256) void k4_mlp(
    const float* __restrict__ accg, const unsigned short* __restrict__ mean16,
    const unsigned short* __restrict__ vw1t, const unsigned short* __restrict__ vw2t,
    const unsigned short* __restrict__ aw1t, const unsigned short* __restrict__ aw2t,
    const float* __restrict__ vb1, const float* __restrict__ vb2,
    const float* __restrict__ ab1, const float* __restrict__ ab2,
    const float* __restrict__ aw3, const float* __restrict__ ab3,
    float* __restrict__ outp){
  __shared__ unsigned short bufE[32*128];
  __shared__ unsigned short bufM[32*128];
  __shared__ unsigned short bufA[32*128];
  __shared__ float fin[4*128];
  __shared__ float lp[32*8];
  __shared__ float att_s[32];
  int t = threadIdx.x, lane = t&63, w = t>>6;
  int R0 = blockIdx.x*32;

  for (int idx=t; idx<4096; idx+=256)
    bufE[idx] = f2h(tanh_fast(accg[(size_t)R0*128 + idx]));
  for (int idx=t; idx<512; idx+=256){
    int r = idx>>4, c8 = (idx&15)<<3;
    int n = R0 + r;
    *(uint4*)(bufM + r*128 + c8) = *(const uint4*)(mean16 + (size_t)(n & 1023)*128 + c8);
  }
  for (int idx=t; idx<512; idx+=256) fin[idx] = 0.f;
  __syncthreads();

  stage<8>(bufE, bufM, aw1t, ab1, bufA, w, lane);
  __syncthreads();
  stage<4>(bufA, nullptr, aw2t, ab2, bufM, w, lane);
  __syncthreads();
  {
    int r = t>>3, seg = t&7;
    float p = 0.f;
    const unsigned short* row = bufM + r*128 + seg*16;
    const float* w3 = aw3 + seg*16;
    #pragma unroll
    for (int k=0;k<16;++k) p += h2f(row[k]) * w3[k];
    lp[r*8+seg] = p;
  }
  __syncthreads();
  if (t < 4){
    float lg[8]; float mx = -1e30f;
    for (int l=0;l<8;++l){
      float s = ab3[0];
      #pragma unroll
      for (int sg=0;sg<8;++sg) s += lp[(t*8+l)*8+sg];
      lg[l] = s; mx = fmaxf(mx, s);
    }
    float sum = 0.f;
    for (int l=0;l<8;++l){ lg[l] = __builtin_amdgcn_exp2f((lg[l]-mx)*1.44269504089f); sum += lg[l]; }
    float inv = __builtin_amdgcn_rcpf(sum);
    for (int l=0;l<8;++l) att_s[t*8+l] = lg[l]*inv;
  }
  __syncthreads();
  stage<4>(bufE, nullptr, vw1t, vb1, bufA, w, lane);
  __syncthreads();
  {
    #pragma unroll
    for (int obl=0; obl<2; ++obl){
      int col = ((w*2+obl)<<4) + (lane&15);
      f32x4 a0 = {0.f,0.f,0.f,0.f}, a1v = {0.f,0.f,0.f,0.f};
      #pragma unroll
      for (int s=0;s<4;++s){
        f16x8 bfr = *(const f16x8*)(vw2t + (size_t)col*128 + s*32 + ((lane>>4)<<3));
        a0  = mfma16(ldsA(bufA,0,s,lane), bfr, a0);
        a1v = mfma16(ldsA(bufA,1,s,lane), bfr, a1v);
      }
      float bb = vb2[col];
      #pragma unroll
      for (int reg=0;reg<4;++reg){
        int r0 = ((lane>>4)<<2) + reg;
        float v0 = tanh_fast(a0[reg]+bb);
        float v1 = tanh_fast(a1v[reg]+bb);
        atomicAdd(&fin[((r0)>>3)*128 + col],    att_s[r0]    * v0);
        atomicAdd(&fin[((16+r0)>>3)*128 + col], att_s[16+r0] * v1);
      }
    }
  }
  __syncthreads();
  for (int idx=t; idx<512; idx+=256){
    int b_loc = idx>>7, o = idx&127;
    outp[(size_t)(R0/8 + b_loc)*128 + o] = fin[idx];
  }
}

// ---------- launch ----------
extern "C" void kernel_launch(void* const* d_in, const int* in_sizes, int n_in,
                              void* d_out, int out_size, void* d_ws, size_t ws_size,
                              hipStream_t stream){
  const float* obs = (const float*)d_in[0];
  const float* hw1 = (const float*)d_in[3];
  const float* hb1 = (const float*)d_in[4];
  const float* hw2 = (const float*)d_in[5];
  const float* hb2 = (const float*)d_in[6];
  const float* vw1 = (const float*)d_in[7];
  const float* vb1 = (const float*)d_in[8];
  const float* vw2 = (const float*)d_in[9];
  const float* vb2 = (const float*)d_in[10];
  const float* aw1 = (const float*)d_in[11];
  const float* ab1 = (const float*)d_in[12];
  const float* aw2 = (const float*)d_in[13];
  const float* ab2 = (const float*)d_in[14];
  const float* aw3 = (const float*)d_in[15];
  const float* ab3 = (const float*)d_in[16];

  char* ws = (char*)d_ws;
  unsigned short* wt2    = (unsigned short*)(ws);             // 3,145,728 B
  unsigned short* mean16 = (unsigned short*)(ws);             //   262,144 B (alias; wt2 dead after k2)
  unsigned short* h16    = (unsigned short*)(ws + 3145728);   // 2,097,152 B
  float*          accg   = (float*)        (ws + 5242880);    // 4,194,304 B
  float*          xT     = (float*)        (ws + 9437184);    // 3,145,728 B
  unsigned short* vw1t   = (unsigned short*)(ws + 12582912);  //    32,768 B
  unsigned short* vw2t   = (unsigned short*)(ws + 12615680);  //    32,768 B
  unsigned short* aw1t   = (unsigned short*)(ws + 12648448);  //    65,536 B
  unsigned short* aw2t   = (unsigned short*)(ws + 12713984);  //    32,768 B  (end 12,746,752)
  float* outp = (float*)d_out;

  hipMemsetAsync(accg, 0, 8192*128*sizeof(float), stream);
  prep_kernel<<<1104, 256, 0, stream>>>(obs, hw1, hb1, hw2, vw1, vw2, aw1, aw2,
                                        wt2, vw1t, vw2t, aw1t, aw2t, h16, xT);
  k2_hyper<<<1024, 256, 0, stream>>>(xT, h16, wt2, hb2, accg);
  k3_mean<<<256, 256, 0, stream>>>(accg, mean16);
  k4_mlp<<<256, 256, 0, stream>>>(accg, mean16, vw1t, vw2t, aw1t, aw2t,
                                  vb1, vb2, ab1, ab2, aw3, ab3, outp);
}